// Round 2
// baseline (880.249 us; speedup 1.0000x reference)
//
#include <hip/hip_runtime.h>
#include <hip/hip_bf16.h>
#include <cstdint>

// Problem constants (fixed by the reference).
#define B_   16
#define C_   306
#define T_   4096
#define M_   270
#define G_   64     // 8x8 grid, strides {8,1}
#define MP   272    // M padded to 17 chunks of 16

#define BDIM 256    // 4 waves per block
#define NW   4      // waves per block
#define TT   64     // t-tile per block (= one wave width)

// ---------------------------------------------------------------------------
// Setup kernel (one launch, does both):
//  (a) per (b,c): packed 4 corner indices + 4 bilinear weights
//  (b) transpose grid_weights [M,64] -> Wt [64][MP] (m-contiguous, zero-pad)
// Corner order matches itertools.product((0,1),repeat=2) with strides {8,1}.
// ---------------------------------------------------------------------------
__global__ void setup_kernel(const float* __restrict__ pos,
                             const float* __restrict__ gw,
                             uint32_t* __restrict__ cidx,
                             float4* __restrict__ cw,
                             float* __restrict__ wt) {
    int i = blockIdx.x * blockDim.x + threadIdx.x;
    if (i < G_ * MP) {
        int g = i / MP;
        int m = i - g * MP;
        wt[i] = (m < M_) ? gw[m * G_ + g] : 0.0f;
    }
    if (i < B_ * C_) {
        float p0 = pos[i * 2 + 0];
        float p1 = pos[i * 2 + 1];
        float gp0 = (p0 + 1.0f) * 4.0f;   // (p+1)*grid_size/2, grid_size=8
        float gp1 = (p1 + 1.0f) * 4.0f;
        float f0 = floorf(gp0), f1 = floorf(gp1);
        int l0 = (int)f0, l1 = (int)f1;
        int h0 = (int)ceilf(gp0), h1 = (int)ceilf(gp1);
        float wh0 = gp0 - f0, wh1 = gp1 - f1;
        float wl0 = 1.0f - wh0, wl1 = 1.0f - wh1;
        uint32_t i00 = (uint32_t)(l0 * 8 + l1);
        uint32_t i01 = (uint32_t)(l0 * 8 + h1);
        uint32_t i10 = (uint32_t)(h0 * 8 + l1);
        uint32_t i11 = (uint32_t)(h0 * 8 + h1);
        cidx[i] = i00 | (i01 << 8) | (i10 << 16) | (i11 << 24);
        cw[i] = make_float4(wl0 * wl1, wl0 * wh1, wh0 * wl1, wh0 * wh1);
    }
}

// ---------------------------------------------------------------------------
// Fused kernel: one block per (b, 64-wide t tile).
//   Phase 1: scatter x[b,c,t]*w into LDS gv[64][64] (indices block-uniform,
//            ds_add_f32 stride-1 -> conflict-free)
//   Phase 2: gv column cached in 64 VGPRs; m processed in chunks of 16 ->
//            16 independent FMA chains; W streamed as 16-float s_loads from
//            the transposed Wt (pipelines across the unrolled g-loop).
// ---------------------------------------------------------------------------
__global__ __launch_bounds__(BDIM, 4) void fused_grid_gemm(
    const float* __restrict__ x, const float* __restrict__ wt,
    const uint32_t* __restrict__ cidx, const float4* __restrict__ cw,
    float* __restrict__ out) {
    __shared__ float gv[G_ * TT];   // [g][t]: lanes stride-1 -> no bank conflicts

    const int b    = blockIdx.y;
    const int t0   = blockIdx.x * TT;
    const int lane = threadIdx.x & 63;
    // readfirstlane: wave id as SGPR so c-offsets / m-chunk bases are provably
    // uniform -> corner data and Wt rows become scalar (s_load) traffic.
    const int wave = __builtin_amdgcn_readfirstlane(threadIdx.x >> 6);
    const int t    = t0 + lane;
    const int bC   = b * C_;

    // zero gv
    for (int i = threadIdx.x; i < G_ * TT; i += BDIM) gv[i] = 0.0f;
    __syncthreads();

    // ---- Phase 1: scatter (waves split the c loop; unroll 8 -> 8 loads in flight)
    const float* xrow = x + (size_t)bC * T_ + t;
    #pragma unroll 8
    for (int c = wave; c < C_; c += NW) {
        uint32_t pk = cidx[bC + c];     // uniform -> s_load
        float4   w  = cw[bC + c];       // uniform -> s_load_dwordx4
        float val = xrow[(size_t)c * T_];   // coalesced across lanes
        atomicAdd(&gv[((pk      ) & 63) * TT + lane], w.x * val);
        atomicAdd(&gv[((pk >>  8) & 63) * TT + lane], w.y * val);
        atomicAdd(&gv[((pk >> 16) & 63) * TT + lane], w.z * val);
        atomicAdd(&gv[((pk >> 24) & 63) * TT + lane], w.w * val);
    }
    __syncthreads();

    // ---- Phase 2 ----
    float gvr[G_];
    #pragma unroll
    for (int g = 0; g < G_; ++g) gvr[g] = gv[g * TT + lane];

    float* op = out + (size_t)b * M_ * T_ + t;
    // rotate chunk->wave mapping per block so the extra 17th chunk doesn't
    // always land on SIMD 0
    const int s = (wave + blockIdx.x) & (NW - 1);
    for (int ci = s; ci < 17; ci += NW) {
        const int m0 = ci << 4;                 // uniform
        const float* wrow = wt + m0;            // uniform base
        float acc[16];
        #pragma unroll
        for (int j = 0; j < 16; ++j) acc[j] = 0.0f;
        #pragma unroll
        for (int g = 0; g < G_; ++g) {
            const float gvv = gvr[g];
            #pragma unroll
            for (int j = 0; j < 16; ++j)
                acc[j] += wrow[g * MP + j] * gvv;   // uniform -> s_load_dwordx4
        }
        #pragma unroll
        for (int j = 0; j < 16; ++j) {
            const int m = m0 + j;
            if (m < M_) op[(size_t)m * T_] = acc[j];
        }
    }
}

extern "C" void kernel_launch(void* const* d_in, const int* in_sizes, int n_in,
                              void* d_out, int out_size, void* d_ws, size_t ws_size,
                              hipStream_t stream) {
    const float* x   = (const float*)d_in[0];
    const float* pos = (const float*)d_in[1];
    const float* gw  = (const float*)d_in[2];
    float* out = (float*)d_out;

    // workspace layout: [ cw: B*C float4 (78336 B) | cidx: B*C u32 (19584 B)
    //                   | pad to 98304 | Wt: 64*272 f32 (69632 B) ]  ~164 KB
    float4*   cw   = (float4*)d_ws;
    uint32_t* cidx = (uint32_t*)((char*)d_ws + (size_t)B_ * C_ * sizeof(float4));
    float*    wtp  = (float*)((char*)d_ws + 98304);

    int setup_threads = G_ * MP;   // 17408 covers both jobs
    setup_kernel<<<(setup_threads + 255) / 256, 256, 0, stream>>>(pos, gw, cidx, cw, wtp);

    dim3 grid(T_ / TT, B_);
    fused_grid_gemm<<<grid, BDIM, 0, stream>>>(x, wtp, cidx, cw, out);
}

// Round 3
// 513.020 us; speedup vs baseline: 1.7158x; 1.7158x over previous
//
#include <hip/hip_runtime.h>
#include <cstdint>

// Problem constants (fixed by the reference).
#define B_   16
#define C_   306
#define T_   4096
#define M_   270
#define G_   64     // 8x8 grid, strides {8,1}
#define MT_  17     // m-tiles of 16 (M padded to 272)
#define TT   64     // t per block
#define GVP  66     // padded LDS row stride (floats) -> only free 2-way conflicts
#define BDIM 256
#define NW   4

typedef __attribute__((ext_vector_type(8))) short s8;   // 8 bf16 (4 VGPRs) MFMA frag
typedef __attribute__((ext_vector_type(4))) float f4;   // 4 fp32 accumulator
typedef __attribute__((ext_vector_type(4))) int   i4;

// fp32 -> bf16 (RNE) as raw bits; and back.
__device__ __forceinline__ short f2bf(float f) {
    unsigned u = __builtin_bit_cast(unsigned, f);
    u += 0x7FFFu + ((u >> 16) & 1u);
    return (short)(u >> 16);
}
__device__ __forceinline__ float bf2f(short h) {
    return __builtin_bit_cast(float, ((unsigned)(unsigned short)h) << 16);
}

// ---------------------------------------------------------------------------
// Setup: (a) per (b,c) packed corner indices + bilinear weights
//        (b) grid_weights -> MFMA A-operand fragments, split hi/lo bf16.
// A-frag layout for mfma_f32_16x16x32_bf16 (verified, learn_hip m120):
//   A[m = lane&15][k = (lane>>4)*8 + j],  j = 0..7  -> 8 bf16 per lane.
// Stored as one 16B record per (mtile, kstep, lane) -> coalesced dwordx4 load.
// ---------------------------------------------------------------------------
__global__ void setup_kernel(const float* __restrict__ pos,
                             const float* __restrict__ gw,
                             uint32_t* __restrict__ cidx,
                             float4* __restrict__ cw,
                             short* __restrict__ whi,
                             short* __restrict__ wlo) {
    int i = blockIdx.x * blockDim.x + threadIdx.x;
    if (i < B_ * C_) {
        float p0 = pos[i * 2 + 0];
        float p1 = pos[i * 2 + 1];
        float gp0 = (p0 + 1.0f) * 4.0f;   // (p+1)*grid_size/2, grid_size=8
        float gp1 = (p1 + 1.0f) * 4.0f;
        float f0 = floorf(gp0), f1 = floorf(gp1);
        int l0 = (int)f0, l1 = (int)f1;
        int h0 = (int)ceilf(gp0), h1 = (int)ceilf(gp1);
        float wh0 = gp0 - f0, wh1 = gp1 - f1;
        float wl0 = 1.0f - wh0, wl1 = 1.0f - wh1;
        uint32_t i00 = (uint32_t)(l0 * 8 + l1);
        uint32_t i01 = (uint32_t)(l0 * 8 + h1);
        uint32_t i10 = (uint32_t)(h0 * 8 + l1);
        uint32_t i11 = (uint32_t)(h0 * 8 + h1);
        cidx[i] = i00 | (i01 << 8) | (i10 << 16) | (i11 << 24);
        cw[i] = make_float4(wl0 * wl1, wl0 * wh1, wh0 * wl1, wh0 * wh1);
    }
    if (i < MT_ * 2 * 64) {               // one thread per (mtile, kstep, lane)
        int lane = i & 63;
        int mt   = i >> 7;                // (i>>6)>>1
        int ks   = (i >> 6) & 1;
        int m    = mt * 16 + (lane & 15);
        int kb   = ks * 32 + (lane >> 4) * 8;
        #pragma unroll
        for (int j = 0; j < 8; ++j) {
            int g = kb + j;
            float w = (m < M_) ? gw[m * G_ + g] : 0.0f;
            short h = f2bf(w);
            whi[i * 8 + j] = h;
            wlo[i * 8 + j] = f2bf(w - bf2f(h));
        }
    }
}

// ---------------------------------------------------------------------------
// Fused kernel, one block per (b, 64-wide t tile):
//  Phase 1: scatter x*w into LDS gv[64][GVP] (stride-1 across lanes, ds_add).
//  Phase 2: out[m,t] = W[m,g]*gv[g,t] via bf16x3 MFMA (fp32-grade accuracy):
//           W = Wh+Wl, gv = Gh+Gl; keep hh + hl + lh terms (ll ~ 2^-16 rel).
//  B-frag: B[k=(lane>>4)*8+j][n=lane&15]; C/D: col(n)=lane&15,
//          row(m)=(lane>>4)*4+reg (verified layouts, learn_hip m89/m120).
// ---------------------------------------------------------------------------
__global__ __launch_bounds__(BDIM) void fused_kernel(
    const float* __restrict__ x, const uint32_t* __restrict__ cidx,
    const float4* __restrict__ cw, const i4* __restrict__ whi,
    const i4* __restrict__ wlo, float* __restrict__ out) {
    __shared__ float gv[G_ * GVP];   // 16.9 KB

    const int b    = blockIdx.y;
    const int t0   = blockIdx.x * TT;
    const int tid  = threadIdx.x;
    const int lane = tid & 63;
    const int wave = __builtin_amdgcn_readfirstlane(tid >> 6);
    const int bC   = b * C_;

    for (int i = tid; i < G_ * GVP; i += BDIM) gv[i] = 0.0f;
    __syncthreads();

    // ---- Phase 1: waves split c; indices block-uniform; lanes stride-1 ----
    const float* xp = x + (size_t)bC * T_ + t0 + lane;
    #pragma unroll 4
    for (int c = wave; c < C_; c += NW) {
        uint32_t pk = cidx[bC + c];
        float4   w  = cw[bC + c];
        float val = xp[(size_t)c * T_];        // coalesced 256B per wave
        atomicAdd(&gv[((pk      ) & 63) * GVP + lane], w.x * val);
        atomicAdd(&gv[((pk >>  8) & 63) * GVP + lane], w.y * val);
        atomicAdd(&gv[((pk >> 16) & 63) * GVP + lane], w.z * val);
        atomicAdd(&gv[((pk >> 24) & 63) * GVP + lane], w.w * val);
    }
    __syncthreads();

    // ---- Phase 2 ----
    const int quad = lane >> 4;
    const int lcol = lane & 15;

    // B fragments (hi/lo) for this block's 4 n-tiles x 2 k-steps.
    // ds_read banks: quads pair up 2-way on the same bank -> free (m136).
    s8 Bh[4][2], Bl[4][2];
    #pragma unroll
    for (int nt = 0; nt < 4; ++nt) {
        #pragma unroll
        for (int ks = 0; ks < 2; ++ks) {
            const int kb = ks * 32 + quad * 8;
            const float* gp = gv + kb * GVP + nt * 16 + lcol;
            #pragma unroll
            for (int j = 0; j < 8; ++j) {
                float v = gp[j * GVP];
                short h = f2bf(v);
                Bh[nt][ks][j] = h;
                Bl[nt][ks][j] = f2bf(v - bf2f(h));
            }
        }
    }

    // m-tiles split across waves; A-frags are per-lane coalesced 16B loads
    // of the precomputed layout (same 139KB for every block -> L2-hot).
    float* op = out + (size_t)b * M_ * T_ + t0;
    for (int mt = wave; mt < MT_; mt += NW) {
        s8 Ah0 = __builtin_bit_cast(s8, whi[(mt * 2 + 0) * 64 + lane]);
        s8 Ah1 = __builtin_bit_cast(s8, whi[(mt * 2 + 1) * 64 + lane]);
        s8 Al0 = __builtin_bit_cast(s8, wlo[(mt * 2 + 0) * 64 + lane]);
        s8 Al1 = __builtin_bit_cast(s8, wlo[(mt * 2 + 1) * 64 + lane]);
        const int mrow = mt * 16 + quad * 4;
        #pragma unroll
        for (int nt = 0; nt < 4; ++nt) {
            f4 acc = {0.f, 0.f, 0.f, 0.f};
            acc = __builtin_amdgcn_mfma_f32_16x16x32_bf16(Al0, Bh[nt][0], acc, 0, 0, 0);
            acc = __builtin_amdgcn_mfma_f32_16x16x32_bf16(Ah0, Bl[nt][0], acc, 0, 0, 0);
            acc = __builtin_amdgcn_mfma_f32_16x16x32_bf16(Ah0, Bh[nt][0], acc, 0, 0, 0);
            acc = __builtin_amdgcn_mfma_f32_16x16x32_bf16(Al1, Bh[nt][1], acc, 0, 0, 0);
            acc = __builtin_amdgcn_mfma_f32_16x16x32_bf16(Ah1, Bl[nt][1], acc, 0, 0, 0);
            acc = __builtin_amdgcn_mfma_f32_16x16x32_bf16(Ah1, Bh[nt][1], acc, 0, 0, 0);
            #pragma unroll
            for (int r = 0; r < 4; ++r) {
                int m = mrow + r;
                if (m < M_)                     // rows 270/271 are pad
                    op[(size_t)m * T_ + nt * 16 + lcol] = acc[r];
            }
        }
    }
}

extern "C" void kernel_launch(void* const* d_in, const int* in_sizes, int n_in,
                              void* d_out, int out_size, void* d_ws, size_t ws_size,
                              hipStream_t stream) {
    const float* x   = (const float*)d_in[0];
    const float* pos = (const float*)d_in[1];
    const float* gw  = (const float*)d_in[2];
    float* out = (float*)d_out;

    // workspace: cw 78336B | cidx 19584B | whi 34816B | wlo 34816B = 167552B
    float4*   cw   = (float4*)d_ws;
    uint32_t* cidx = (uint32_t*)((char*)d_ws + 78336);
    short*    whi  = (short*)((char*)d_ws + 97920);
    short*    wlo  = (short*)((char*)d_ws + 132736);

    setup_kernel<<<(B_ * C_ + 255) / 256, 256, 0, stream>>>(pos, gw, cidx, cw, whi, wlo);

    dim3 grid(T_ / TT, B_);
    fused_kernel<<<grid, BDIM, 0, stream>>>(x, cidx, cw, (const i4*)whi, (const i4*)wlo, out);
}

// Round 4
// 235.865 us; speedup vs baseline: 3.7320x; 2.1751x over previous
//
#include <hip/hip_runtime.h>
#include <cstdint>

// Problem constants (fixed by the reference).
#define B_   16
#define C_   306
#define T_   4096
#define M_   270
#define G_   64     // 8x8 grid, strides {8,1}
#define E_   1224   // entries per b = 4*C_ (every c contributes exactly 4 corners)
#define MT_  17     // m-tiles of 16 (M padded to 272)
#define TT   64     // t per block
#define GVP  66     // padded LDS row stride (floats) -> only free 2-way conflicts
#define BDIM 256
#define NW   4

typedef __attribute__((ext_vector_type(8))) short s8;   // 8 bf16 (4 VGPRs) MFMA frag
typedef __attribute__((ext_vector_type(4))) float f4;   // 4 fp32 accumulator
typedef __attribute__((ext_vector_type(4))) int   i4;

// fp32 -> bf16 (RNE) as raw bits; and back.
__device__ __forceinline__ short f2bf(float f) {
    unsigned u = __builtin_bit_cast(unsigned, f);
    u += 0x7FFFu + ((u >> 16) & 1u);
    return (short)(u >> 16);
}
__device__ __forceinline__ float bf2f(short h) {
    return __builtin_bit_cast(float, ((unsigned)(unsigned short)h) << 16);
}

// ---------------------------------------------------------------------------
// Setup A: per-b CSR bucketing of (c, bilinear weight) by grid row g.
// One 64-thread block (one wave) per b. INT LDS atomics only (native ds ops).
// entries[b*E_ + k] = { c, bitcast(weight) }, offsets[b*65 + g] = bucket start.
// Corner order/strides match itertools.product((0,1),repeat=2), strides {8,1}.
// ---------------------------------------------------------------------------
__global__ __launch_bounds__(64) void setup_csr(const float* __restrict__ pos,
                                                int2* __restrict__ entries,
                                                int* __restrict__ offsets) {
    __shared__ int cnt[G_], offs[G_ + 1], cur[G_];
    const int b = blockIdx.x;
    const int lane = threadIdx.x;

    cnt[lane] = 0;
    __syncthreads();

    // pass 1: count corners per row
    for (int c = lane; c < C_; c += 64) {
        int i = b * C_ + c;
        float gp0 = (pos[i * 2 + 0] + 1.0f) * 4.0f;
        float gp1 = (pos[i * 2 + 1] + 1.0f) * 4.0f;
        int l0 = (int)floorf(gp0), l1 = (int)floorf(gp1);
        int h0 = (int)ceilf(gp0),  h1 = (int)ceilf(gp1);
        atomicAdd(&cnt[l0 * 8 + l1], 1);
        atomicAdd(&cnt[l0 * 8 + h1], 1);
        atomicAdd(&cnt[h0 * 8 + l1], 1);
        atomicAdd(&cnt[h0 * 8 + h1], 1);
    }
    __syncthreads();

    // exclusive scan (64 rows, serial on lane 0 -- trivial size)
    if (lane == 0) {
        int s = 0;
        for (int g = 0; g < G_; ++g) { offs[g] = s; s += cnt[g]; }
        offs[G_] = s;   // == E_
    }
    __syncthreads();

    offsets[b * 65 + lane] = offs[lane];
    if (lane == 63) offsets[b * 65 + 64] = offs[64];
    cur[lane] = offs[lane];
    __syncthreads();

    // pass 2: scatter entries
    for (int c = lane; c < C_; c += 64) {
        int i = b * C_ + c;
        float gp0 = (pos[i * 2 + 0] + 1.0f) * 4.0f;
        float gp1 = (pos[i * 2 + 1] + 1.0f) * 4.0f;
        float f0 = floorf(gp0), f1 = floorf(gp1);
        int l0 = (int)f0, l1 = (int)f1;
        int h0 = (int)ceilf(gp0), h1 = (int)ceilf(gp1);
        float wh0 = gp0 - f0, wh1 = gp1 - f1;
        float wl0 = 1.0f - wh0, wl1 = 1.0f - wh1;
        int   gi[4] = { l0 * 8 + l1, l0 * 8 + h1, h0 * 8 + l1, h0 * 8 + h1 };
        float wv[4] = { wl0 * wl1,   wl0 * wh1,   wh0 * wl1,   wh0 * wh1 };
        #pragma unroll
        for (int k = 0; k < 4; ++k) {
            int p = atomicAdd(&cur[gi[k]], 1);
            entries[b * E_ + p] = make_int2(c, __builtin_bit_cast(int, wv[k]));
        }
    }
}

// ---------------------------------------------------------------------------
// Setup B: grid_weights -> MFMA A-operand fragments, split hi/lo bf16.
// A[m=lane&15][k=(lane>>4)*8+j] per 16B record -> coalesced dwordx4 load.
// ---------------------------------------------------------------------------
__global__ void setup_frags(const float* __restrict__ gw,
                            short* __restrict__ whi,
                            short* __restrict__ wlo) {
    int i = blockIdx.x * blockDim.x + threadIdx.x;
    if (i >= MT_ * 2 * 64) return;
    int lane = i & 63;
    int mt   = i >> 7;
    int ks   = (i >> 6) & 1;
    int m    = mt * 16 + (lane & 15);
    int kb   = ks * 32 + (lane >> 4) * 8;
    #pragma unroll
    for (int j = 0; j < 8; ++j) {
        float w = (m < M_) ? gw[m * G_ + kb + j] : 0.0f;
        short h = f2bf(w);
        whi[i * 8 + j] = h;
        wlo[i * 8 + j] = f2bf(w - bf2f(h));
    }
}

// ---------------------------------------------------------------------------
// Fused kernel, one block per (b, 64-wide t tile):
//  Phase 1 (GATHER, no atomics): wave w owns rows g == w (mod 4). For each
//    owned row, register-accumulate sum_{(c,wgt) in bucket[g]} wgt * x[c,t],
//    then one plain ds_write. Loads feed FMAs directly -> deep pipelining.
//  Phase 2: out[m,t] = W[m,g]*gv[g,t] via bf16x3 MFMA (verified in R3,
//    absmax 0.25): W=Wh+Wl, gv=Gh+Gl, keep hh+hl+lh terms.
// ---------------------------------------------------------------------------
__global__ __launch_bounds__(BDIM) void fused_kernel(
    const float* __restrict__ x, const int2* __restrict__ entries,
    const int* __restrict__ offsets, const i4* __restrict__ whi,
    const i4* __restrict__ wlo, float* __restrict__ out) {
    __shared__ float gv[G_ * GVP];   // 16.9 KB

    const int b    = blockIdx.y;
    const int t0   = blockIdx.x * TT;
    const int tid  = threadIdx.x;
    const int lane = tid & 63;
    const int wave = __builtin_amdgcn_readfirstlane(tid >> 6);

    // ---- Phase 1: CSR gather ----
    const float* xb = x + (size_t)b * C_ * T_ + t0 + lane;
    const int2*  eb = entries + b * E_;
    const int*   ob = offsets + b * 65;
    #pragma unroll
    for (int i = 0; i < 16; ++i) {
        const int g  = wave + i * NW;       // wave-uniform row
        const int e0 = ob[g];
        const int e1 = ob[g + 1];
        float acc = 0.0f;
        #pragma unroll 4
        for (int e = e0; e < e1; ++e) {
            int2 ent = eb[e];               // uniform -> scalar path
            acc += __builtin_bit_cast(float, ent.y) * xb[(size_t)ent.x * T_];
        }
        gv[g * GVP + lane] = acc;           // exclusive owner: plain write
    }
    __syncthreads();

    // ---- Phase 2 (unchanged from R3) ----
    const int quad = lane >> 4;
    const int lcol = lane & 15;

    s8 Bh[4][2], Bl[4][2];
    #pragma unroll
    for (int nt = 0; nt < 4; ++nt) {
        #pragma unroll
        for (int ks = 0; ks < 2; ++ks) {
            const int kb = ks * 32 + quad * 8;
            const float* gp = gv + kb * GVP + nt * 16 + lcol;
            #pragma unroll
            for (int j = 0; j < 8; ++j) {
                float v = gp[j * GVP];
                short h = f2bf(v);
                Bh[nt][ks][j] = h;
                Bl[nt][ks][j] = f2bf(v - bf2f(h));
            }
        }
    }

    float* op = out + (size_t)b * M_ * T_ + t0;
    for (int mt = wave; mt < MT_; mt += NW) {
        s8 Ah0 = __builtin_bit_cast(s8, whi[(mt * 2 + 0) * 64 + lane]);
        s8 Ah1 = __builtin_bit_cast(s8, whi[(mt * 2 + 1) * 64 + lane]);
        s8 Al0 = __builtin_bit_cast(s8, wlo[(mt * 2 + 0) * 64 + lane]);
        s8 Al1 = __builtin_bit_cast(s8, wlo[(mt * 2 + 1) * 64 + lane]);
        const int mrow = mt * 16 + quad * 4;
        #pragma unroll
        for (int nt = 0; nt < 4; ++nt) {
            f4 acc = {0.f, 0.f, 0.f, 0.f};
            acc = __builtin_amdgcn_mfma_f32_16x16x32_bf16(Al0, Bh[nt][0], acc, 0, 0, 0);
            acc = __builtin_amdgcn_mfma_f32_16x16x32_bf16(Ah0, Bl[nt][0], acc, 0, 0, 0);
            acc = __builtin_amdgcn_mfma_f32_16x16x32_bf16(Ah0, Bh[nt][0], acc, 0, 0, 0);
            acc = __builtin_amdgcn_mfma_f32_16x16x32_bf16(Al1, Bh[nt][1], acc, 0, 0, 0);
            acc = __builtin_amdgcn_mfma_f32_16x16x32_bf16(Ah1, Bl[nt][1], acc, 0, 0, 0);
            acc = __builtin_amdgcn_mfma_f32_16x16x32_bf16(Ah1, Bh[nt][1], acc, 0, 0, 0);
            #pragma unroll
            for (int r = 0; r < 4; ++r) {
                int m = mrow + r;
                if (m < M_)                     // rows 270/271 are pad
                    op[(size_t)m * T_ + nt * 16 + lcol] = acc[r];
            }
        }
    }
}

extern "C" void kernel_launch(void* const* d_in, const int* in_sizes, int n_in,
                              void* d_out, int out_size, void* d_ws, size_t ws_size,
                              hipStream_t stream) {
    const float* x   = (const float*)d_in[0];
    const float* pos = (const float*)d_in[1];
    const float* gw  = (const float*)d_in[2];
    float* out = (float*)d_out;

    // workspace: entries 16*1224*8 = 156672 B | offsets 16*65*4 = 4160 B
    //            | whi 34816 B | wlo 34816 B   -> ~225 KB total
    int2*  entries = (int2*)d_ws;
    int*   offsets = (int*)((char*)d_ws + 156672);
    short* whi     = (short*)((char*)d_ws + 160832);
    short* wlo     = (short*)((char*)d_ws + 195648);

    setup_csr<<<B_, 64, 0, stream>>>(pos, entries, offsets);
    setup_frags<<<(MT_ * 2 * 64 + 255) / 256, 256, 0, stream>>>(gw, whi, wlo);

    dim3 grid(T_ / TT, B_);
    fused_kernel<<<grid, BDIM, 0, stream>>>(x, entries, offsets,
                                            (const i4*)whi, (const i4*)wlo, out);
}